// Round 3
// baseline (87.599 us; speedup 1.0000x reference)
//
#include <hip/hip_runtime.h>

// RotMat forward: 511 rounds of 256 disjoint Givens rotations on rows of a
// [512, 1024] fp32 matrix (round-robin tournament schedule).
//
// Position-space formulation: position k always pairs with position 511-k;
// between rounds values undergo a fixed cyclic shift. Pair-space recursion:
//   L^new_0 = L'_0; L^new_1 = H'_0; L^new_k = L'_{k-1} (k>=2)
//   H^new_k = H'_{k+1} (k<=254); H^new_255 = L'_255
// After 511 rounds the permutation is identity -> store by row index.
//
// R2 change: 2-round halo batching. R1 measured 352 cy/round with only ~93 cy
// of VALU issue -> ~260 cy of exposed ds_bpermute latency per round (1 wave/
// SIMD, no TLP). Now each lane pulls a +-2-pair halo (8 bpermutes, ONE lgkm
// wait per 2 rounds) and computes two rounds locally, redundantly rotating
// halo pairs (14 rotations / 2 rounds vs 8).

#define N_COLS   1024
#define PAIRS    256

// cs[r*256+k] = (cos(th), +-sin(th)); sign + if lo position's player is the
// lower row index.
__global__ __launch_bounds__(256) void rotmat_setup(const float* __restrict__ thetas,
                                                    float2* __restrict__ cs) {
    const int r = blockIdx.x;   // 0..510
    const int k = threadIdx.x;  // 0..255
    int pu = (k == 0) ? 0 : ((k - 1 - r + 1022) % 511) + 1;
    int pv = ((510 - k - r + 1022) % 511) + 1;
    int i = min(pu, pv), j = max(pu, pv);
    int t = i * 511 - (i * (i - 1)) / 2 + (j - i - 1);
    float s, c;
    sincosf(thetas[t], &s, &c);
    float sp = (pu < pv) ? s : -s;
    cs[r * PAIRS + k] = make_float2(c, sp);
}

__device__ __forceinline__ float bperm(int addr, float x) {
    return __int_as_float(__builtin_amdgcn_ds_bpermute(addr, __float_as_int(x)));
}

#define ROTP(C, S, Lx, Hx, LPx, HPx)            \
    {                                           \
        float _t = (S) * (Hx);                  \
        (LPx) = fmaf((C), (Lx), -_t);           \
        float _u = (S) * (Lx);                  \
        (HPx) = fmaf((C), (Hx), _u);            \
    }

// c/s of window slot s from a 4x float4 window (2 pairs per float4)
#define CSX(W, s) (((s) & 1) ? (W)[(s) >> 1].z : (W)[(s) >> 1].x)
#define CSY(W, s) (((s) & 1) ? (W)[(s) >> 1].w : (W)[(s) >> 1].y)

// One 2-round batch. WA/WB: cs windows for rounds 2b, 2b+1. PREBASE: float4
// base index of the batch to prefetch into the same ring regs (already
// clamped). Uses/updates Lo[4], Ho[4]; reads lane-const b4[], upA, dnA,
// is0, is63, T4.
#define DO_BATCH(WA, WB, PREBASE)                                              \
    {                                                                          \
        float LW[8], HW[8];                                                    \
        LW[0] = bperm(upA, Lo[2]); LW[1] = bperm(upA, Lo[3]);                  \
        HW[0] = bperm(upA, Ho[2]); HW[1] = bperm(upA, Ho[3]);                  \
        LW[6] = bperm(dnA, Lo[0]); LW[7] = bperm(dnA, Lo[1]);                  \
        HW[6] = bperm(dnA, Ho[0]); HW[7] = bperm(dnA, Ho[1]);                  \
        LW[2] = Lo[0]; LW[3] = Lo[1]; LW[4] = Lo[2]; LW[5] = Lo[3];            \
        HW[2] = Ho[0]; HW[3] = Ho[1]; HW[4] = Ho[2]; HW[5] = Ho[3];            \
        float LP[8], HP[8];                                                    \
        _Pragma("unroll")                                                      \
        for (int s2 = 2; s2 <= 5; ++s2) {  /* own slots first (no lgkm dep) */ \
            ROTP(CSX(WA, s2), CSY(WA, s2), LW[s2], HW[s2], LP[s2], HP[s2])     \
        }                                                                      \
        ROTP(CSX(WA, 0), CSY(WA, 0), LW[0], HW[0], LP[0], HP[0])               \
        ROTP(CSX(WA, 1), CSY(WA, 1), LW[1], HW[1], LP[1], HP[1])               \
        ROTP(CSX(WA, 6), CSY(WA, 6), LW[6], HW[6], LP[6], HP[6])               \
        ROTP(CSX(WA, 7), CSY(WA, 7), LW[7], HW[7], LP[7], HP[7])               \
        float LA[7], HA[7];                                                    \
        LA[1] = LP[0];                                                         \
        LA[2] = is0 ? LP[2] : LP[1];                                           \
        LA[3] = is0 ? HP[2] : LP[2];                                           \
        LA[4] = LP[3]; LA[5] = LP[4]; LA[6] = LP[5];                           \
        HA[1] = HP[2]; HA[2] = HP[3]; HA[3] = HP[4]; HA[4] = HP[5];            \
        HA[5] = is63 ? LP[5] : HP[6];                                          \
        HA[6] = HP[7];                                                         \
        float LB[7], HB[7];                                                    \
        _Pragma("unroll")                                                      \
        for (int s2 = 1; s2 <= 6; ++s2) {                                      \
            ROTP(CSX(WB, s2), CSY(WB, s2), LA[s2], HA[s2], LB[s2], HB[s2])     \
        }                                                                      \
        Lo[0] = is0 ? LB[2] : LB[1];                                           \
        Lo[1] = is0 ? HB[2] : LB[2];                                           \
        Lo[2] = LB[3]; Lo[3] = LB[4];                                          \
        Ho[0] = HB[3]; Ho[1] = HB[4]; Ho[2] = HB[5];                           \
        Ho[3] = is63 ? LB[5] : HB[6];                                          \
        _Pragma("unroll")                                                      \
        for (int j2 = 0; j2 < 4; ++j2) {  /* prefetch next ring slot */        \
            (WA)[j2] = T4[(PREBASE) + b4[j2]];                                 \
            (WB)[j2] = T4[(PREBASE) + 128 + b4[j2]];                           \
        }                                                                      \
    }

template <bool TAB>
__global__ __launch_bounds__(256) void rotmat_main(const float* __restrict__ x,
                                                   const float* __restrict__ thetas,
                                                   const float2* __restrict__ cs,
                                                   float* __restrict__ out) {
    const int lane = threadIdx.x & 63;
    const int wave = threadIdx.x >> 6;
    const int col  = (blockIdx.x << 2) + wave;  // one column per wave
    const int k0   = lane << 2;                 // first pair index of this lane

    float Lo[4], Ho[4];
#pragma unroll
    for (int m = 0; m < 4; ++m) {
        Lo[m] = x[(k0 + m) * N_COLS + col];
        Ho[m] = x[(511 - k0 - m) * N_COLS + col];
    }

    if constexpr (TAB) {
        const float4* T4 = reinterpret_cast<const float4*>(cs);
        // cs float4 offsets for the lane's 8-pair window [4l-2, 4l+5],
        // clamped to valid float2 range [0,254] (clamped entries feed only
        // garbage halo slots of lanes 0/63; alignment preserved).
        int b4[4];
#pragma unroll
        for (int j = 0; j < 4; ++j) {
            int f2o = 4 * lane - 2 + 2 * j;
            f2o = max(0, min(f2o, 254));
            b4[j] = f2o >> 1;
        }
        const int upA = ((lane + 63) & 63) << 2;  // bpermute addr: lane-1 (wraps; wrapped vals unused)
        const int dnA = ((lane + 1) & 63) << 2;   // lane+1
        const bool is0 = (lane == 0), is63 = (lane == 63);

        // Ring of 3 batches (rows 2b, 2b+1 -> float4 bases 256b, 256b+128).
        float4 rA0[4], rB0[4], rA1[4], rB1[4], rA2[4], rB2[4];
#pragma unroll
        for (int j = 0; j < 4; ++j) {
            rA0[j] = T4[b4[j]];           rB0[j] = T4[128 + b4[j]];
            rA1[j] = T4[256 + b4[j]];     rB1[j] = T4[256 + 128 + b4[j]];
            rA2[j] = T4[512 + b4[j]];     rB2[j] = T4[512 + 128 + b4[j]];
        }
        // cs for the final single round (510), prefetched now.
        float4 cL0 = T4[510 * 128 + 2 * lane];
        float4 cL1 = T4[510 * 128 + 2 * lane + 1];

        // 255 batches = rounds 0..509 (85 x 3-deep ring).
        int b = 0;
        for (int bt = 0; bt < 85; ++bt) {
            {
                int p = 256 * min(b + 3, 254);
                DO_BATCH(rA0, rB0, p)
                ++b;
            }
            {
                int p = 256 * min(b + 3, 254);
                DO_BATCH(rA1, rB1, p)
                ++b;
            }
            {
                int p = 256 * min(b + 3, 254);
                DO_BATCH(rA2, rB2, p)
                ++b;
            }
        }

        // Round 510 (single): rotate own pairs, then shift.
        {
            float l0, h0, l1, h1, l2, h2, l3, h3;
            ROTP(cL0.x, cL0.y, Lo[0], Ho[0], l0, h0)
            ROTP(cL0.z, cL0.w, Lo[1], Ho[1], l1, h1)
            ROTP(cL1.x, cL1.y, Lo[2], Ho[2], l2, h2)
            ROTP(cL1.z, cL1.w, Lo[3], Ho[3], l3, h3)
            float up = bperm(upA, l3);
            float dn = bperm(dnA, h0);
            float nlo0 = is0 ? l0 : up;
            float nlo1 = is0 ? h0 : l0;
            float nhi3 = is63 ? l3 : dn;
            Lo[3] = l2; Lo[2] = l1; Lo[1] = nlo1; Lo[0] = nlo0;
            Ho[0] = h1; Ho[1] = h2; Ho[2] = h3; Ho[3] = nhi3;
        }
    } else {
        // Fallback: compute schedule + sincos inline (no workspace table).
        int pu[4], pv[4];
#pragma unroll
        for (int m = 0; m < 4; ++m) {
            pu[m] = (k0 + m == 0) ? 0 : (k0 + m);
            pv[m] = 511 - (k0 + m);
        }
        for (int r = 0; r < 511; ++r) {
#pragma unroll
            for (int m = 0; m < 4; ++m) {
                int i = min(pu[m], pv[m]), j = max(pu[m], pv[m]);
                int t = i * 511 - (i * (i - 1)) / 2 + (j - i - 1);
                float s, c;
                sincosf(thetas[t], &s, &c);
                float sp = (pu[m] < pv[m]) ? s : -s;
                float L = Lo[m], H = Ho[m];
                Lo[m] = fmaf(c, L, -(sp * H));
                Ho[m] = fmaf(c, H, sp * L);
            }
            {
                float up = __shfl_up(Lo[3], 1);
                float dn = __shfl_down(Ho[0], 1);
                float nlo0 = (lane == 0) ? Lo[0] : up;
                float nlo1 = (lane == 0) ? Ho[0] : Lo[0];
                float nhi3 = (lane == 63) ? Lo[3] : dn;
                Lo[3] = Lo[2]; Lo[2] = Lo[1]; Lo[1] = nlo1; Lo[0] = nlo0;
                Ho[0] = Ho[1]; Ho[1] = Ho[2]; Ho[2] = Ho[3]; Ho[3] = nhi3;
            }
#pragma unroll
            for (int m = 0; m < 4; ++m) {
                pu[m] = (k0 + m == 0) ? 0 : ((pu[m] == 1) ? 511 : pu[m] - 1);
                pv[m] = (pv[m] == 1) ? 511 : pv[m] - 1;
            }
        }
    }

    // After 511 shifts the position->row permutation is identity.
#pragma unroll
    for (int m = 0; m < 4; ++m) {
        out[(k0 + m) * N_COLS + col]       = Lo[m];
        out[(511 - k0 - m) * N_COLS + col] = Ho[m];
    }
}

extern "C" void kernel_launch(void* const* d_in, const int* in_sizes, int n_in,
                              void* d_out, int out_size, void* d_ws, size_t ws_size,
                              hipStream_t stream) {
    const float* x  = (const float*)d_in[0];
    const float* th = (const float*)d_in[1];
    float* out      = (float*)d_out;

    const size_t need = (size_t)512 * PAIRS * sizeof(float2);  // 1 MiB
    if (ws_size >= need) {
        float2* cs = (float2*)d_ws;
        rotmat_setup<<<511, PAIRS, 0, stream>>>(th, cs);
        rotmat_main<true><<<N_COLS / 4, 256, 0, stream>>>(x, th, cs, out);
    } else {
        rotmat_main<false><<<N_COLS / 4, 256, 0, stream>>>(x, th, nullptr, out);
    }
}

// Round 4
// 60.086 us; speedup vs baseline: 1.4579x; 1.4579x over previous
//
#include <hip/hip_runtime.h>

// RotMat forward: 511 rounds of 256 disjoint Givens rotations on rows of a
// [512, 1024] fp32 matrix (round-robin tournament schedule).
//
// Position-space formulation: position k always pairs with position 511-k;
// between rounds the values undergo a fixed cyclic shift (v[0] fixed,
// v[p]->v[p+1] for p=1..510, v[511]->v[1]). After 511 shifts the permutation
// is the identity, so the final store is by row index directly.
//
// Layout: 1 column per wave (64 lanes), lane l owns pairs k=4l..4l+3.
// R1: 16-round register ring buffer for the cos/sin table (32 loads in
// flight; killed the ~900cy/round HBM latency of R0).
// R3: replace the per-round ds_bpermute lane-shifts (LDS pipe, ~120cy,
// serially dependent round-to-round, 1 wave/SIMD -> fully exposed; measured
// ~260 cy/round) with DPP wave_shr:1 / wave_shl:1 (VALU, ~4cy). update_dpp's
// `old` operand (bound_ctrl=0: OOB lanes keep old) gives the lane-0/63 edge
// fixups for free. R2's 2-round halo batching regressed (VGPR pressure
// collapsed the prefetch ring) and is reverted.

#define N_ROWS   512
#define N_COLS   1024
#define R_ROUNDS 511
#define PAIRS    256
#define DEPTH    16

// Precompute cs[r*256+k] = (cos(th), +-sin(th)) where the sign is + if the
// lo position's player is the lower row index i, else -.
__global__ __launch_bounds__(256) void rotmat_setup(const float* __restrict__ thetas,
                                                    float2* __restrict__ cs) {
    const int r = blockIdx.x;   // 0..510
    const int k = threadIdx.x;  // 0..255
    // player at position p in round r: p==0 -> 0 else ((p-1-r) mod 511)+1
    int pu = (k == 0) ? 0 : ((k - 1 - r + 1022) % 511) + 1;
    int pv = ((510 - k - r + 1022) % 511) + 1;
    int i = min(pu, pv), j = max(pu, pv);
    int t = i * 511 - (i * (i - 1)) / 2 + (j - i - 1);
    float s, c;
    sincosf(thetas[t], &s, &c);
    float sp = (pu < pv) ? s : -s;
    cs[r * PAIRS + k] = make_float2(c, sp);
}

// DPP wave-shift helpers. gfx9-lineage (CDNA4) keeps wave_* DPP modes.
// WAVE_SHR1 (0x138): lane i <- lane i-1, lane 0 OOB -> keeps `old`.
// WAVE_SHL1 (0x130): lane i <- lane i+1, lane 63 OOB -> keeps `old`.
__device__ __forceinline__ float dpp_shr1(float old, float src) {
    return __int_as_float(__builtin_amdgcn_update_dpp(
        __float_as_int(old), __float_as_int(src), 0x138, 0xF, 0xF, false));
}
__device__ __forceinline__ float dpp_shl1(float old, float src) {
    return __int_as_float(__builtin_amdgcn_update_dpp(
        __float_as_int(old), __float_as_int(src), 0x130, 0xF, 0xF, false));
}

#define ROT(mi, C, S)                                   \
    {                                                   \
        float L = lo[mi], H = hi[mi];                   \
        lo[mi] = fmaf((C), L, -(S) * H);                \
        hi[mi] = fmaf((C), H, (S) * L);                 \
    }

// Shift: lo[0]<-lane-1's lo[3] (lane0: keeps lo[0]); lo[1]<-lo[0] (lane0:
// hi[0]); interior renames; hi[3]<-lane+1's hi[0] (lane63: lo[3]).
#define SHIFT()                                                   \
    {                                                             \
        float nlo0 = dpp_shr1(lo[0], lo[3]);                      \
        float nhi3 = dpp_shl1(lo[3], hi[0]);                      \
        float nlo1 = is0 ? hi[0] : lo[0];                         \
        lo[3] = lo[2]; lo[2] = lo[1]; lo[1] = nlo1; lo[0] = nlo0; \
        hi[0] = hi[1]; hi[1] = hi[2]; hi[2] = hi[3]; hi[3] = nhi3;\
    }

#define ROUND(AA, BB)            \
    ROT(0, (AA).x, (AA).y)       \
    ROT(1, (AA).z, (AA).w)       \
    ROT(2, (BB).x, (BB).y)       \
    ROT(3, (BB).z, (BB).w)       \
    SHIFT()

template <bool TAB>
__global__ __launch_bounds__(256) void rotmat_main(const float* __restrict__ x,
                                                   const float* __restrict__ thetas,
                                                   const float2* __restrict__ cs,
                                                   float* __restrict__ out) {
    const int lane = threadIdx.x & 63;
    const int wave = threadIdx.x >> 6;
    const int col  = (blockIdx.x << 2) + wave;  // one column per wave
    const int k0   = lane << 2;                 // first pair index of this lane
    const bool is0 = (lane == 0);

    float lo[4], hi[4];
#pragma unroll
    for (int m = 0; m < 4; ++m) {
        lo[m] = x[(k0 + m) * N_COLS + col];
        hi[m] = x[(511 - k0 - m) * N_COLS + col];
    }

    if constexpr (TAB) {
        // 128 float4 per round; lane reads 2 consecutive float4 (32B).
        const float4* base = reinterpret_cast<const float4*>(cs) + (lane << 1);
        float4 A[DEPTH], B[DEPTH];
#pragma unroll
        for (int u = 0; u < DEPTH; ++u) {
            A[u] = base[u * 128];
            B[u] = base[u * 128 + 1];
        }
        // 31 blocks of 16 rounds = rounds 0..495; loads issued for rounds
        // 16..511 (table padded to 512 rounds; round 511 loaded, unused).
        for (int rb = 0; rb < 496; rb += DEPTH) {
#pragma unroll
            for (int u = 0; u < DEPTH; ++u) {
                ROUND(A[u], B[u])
                A[u] = base[(rb + DEPTH + u) * 128];
                B[u] = base[(rb + DEPTH + u) * 128 + 1];
            }
        }
        // Remainder: rounds 496..510 from A[0..14] (loaded at rb=480).
#pragma unroll
        for (int u = 0; u < DEPTH - 1; ++u) {
            ROUND(A[u], B[u])
        }
    } else {
        // Fallback: compute schedule + sincos inline (no workspace table).
        int pu[4], pv[4];
#pragma unroll
        for (int m = 0; m < 4; ++m) {
            pu[m] = (k0 + m == 0) ? 0 : (k0 + m);
            pv[m] = 511 - (k0 + m);
        }
        for (int r = 0; r < R_ROUNDS; ++r) {
#pragma unroll
            for (int m = 0; m < 4; ++m) {
                int i = min(pu[m], pv[m]), j = max(pu[m], pv[m]);
                int t = i * 511 - (i * (i - 1)) / 2 + (j - i - 1);
                float s, c;
                sincosf(thetas[t], &s, &c);
                float sp = (pu[m] < pv[m]) ? s : -s;
                ROT(m, c, sp)
            }
            SHIFT()
#pragma unroll
            for (int m = 0; m < 4; ++m) {
                pu[m] = (k0 + m == 0) ? 0 : ((pu[m] == 1) ? 511 : pu[m] - 1);
                pv[m] = (pv[m] == 1) ? 511 : pv[m] - 1;
            }
        }
    }

    // After 511 shifts the position->row permutation is identity.
#pragma unroll
    for (int m = 0; m < 4; ++m) {
        out[(k0 + m) * N_COLS + col]       = lo[m];
        out[(511 - k0 - m) * N_COLS + col] = hi[m];
    }
}

extern "C" void kernel_launch(void* const* d_in, const int* in_sizes, int n_in,
                              void* d_out, int out_size, void* d_ws, size_t ws_size,
                              hipStream_t stream) {
    const float* x  = (const float*)d_in[0];
    const float* th = (const float*)d_in[1];
    float* out      = (float*)d_out;

    // Table: 512 rounds padded (pipeline reads one past the last round).
    const size_t need = (size_t)512 * PAIRS * sizeof(float2);  // 1 MiB
    if (ws_size >= need) {
        float2* cs = (float2*)d_ws;
        rotmat_setup<<<R_ROUNDS, PAIRS, 0, stream>>>(th, cs);
        rotmat_main<true><<<N_COLS / 4, 256, 0, stream>>>(x, th, cs, out);
    } else {
        rotmat_main<false><<<N_COLS / 4, 256, 0, stream>>>(x, th, nullptr, out);
    }
}

// Round 5
// 58.678 us; speedup vs baseline: 1.4929x; 1.0240x over previous
//
#include <hip/hip_runtime.h>

// RotMat forward: 511 rounds of 256 disjoint Givens rotations on rows of a
// [512, 1024] fp32 matrix (round-robin tournament schedule).
//
// Position-space formulation: position k pairs with 511-k every round; between
// rounds values shift cyclically (pair-space: L[k]<-L[k-1], H[k]<-H[k+1] with
// end specials). After 511 rounds the permutation is identity.
//
// Ladder: R0 177us (no prefetch, ~900cy/round HBM latency). R1 75us (register
// ring -- but VGPR cap collapsed depth to ~6). R3 60us (DPP shifts replace
// ds_bpermute). R4: table staged via global_load_lds into double-buffered LDS
// chunks (16 rounds = 32KB each), counted vmcnt(8) + raw s_barrier (T3/T4
// pattern; __syncthreads would drain vmcnt(0)). Prefetch depth now ~16 rounds
// independent of the register allocator; 4 waves/block share one staged copy.
// Inner: 4-round ds_read ring (static idx), conflict-free plane layout,
// immediate-offset ds_read_b128.

#define N_COLS      1024
#define PAIRS       256
#define CHUNK       16                 // rounds per chunk
#define CHUNK_BYTES (CHUNK * 2048)     // 32 KB (2KB per round)

// Table layout (plane form): float2 index = r*256 + plane*128 + lane*2 + slot
// where pair k -> plane=(k>>1)&1, lane=k>>2, slot=k&1. Lane l's round-r data:
// planeA float4 = pairs 4l,4l+1 at f4 idx r*128 + l; planeB = pairs 4l+2,4l+3
// at r*128 + 64 + l. Both ds_read_b128 stride-16B across lanes (conflict-free).
__global__ __launch_bounds__(256) void rotmat_setup(const float* __restrict__ thetas,
                                                    float2* __restrict__ cs) {
    const int r = blockIdx.x;   // 0..510
    const int k = threadIdx.x;  // 0..255 (pair index)
    int pu = (k == 0) ? 0 : ((k - 1 - r + 1022) % 511) + 1;
    int pv = ((510 - k - r + 1022) % 511) + 1;
    int i = min(pu, pv), j = max(pu, pv);
    int t = i * 511 - (i * (i - 1)) / 2 + (j - i - 1);
    float s, c;
    sincosf(thetas[t], &s, &c);
    float sp = (pu < pv) ? s : -s;
    int plane = (k >> 1) & 1, ln = k >> 2, slot = k & 1;
    cs[r * 256 + plane * 128 + ln * 2 + slot] = make_float2(c, sp);
}

// DPP wave-shift helpers (gfx9 lineage). WAVE_SHR1 0x138: lane i <- i-1, lane0
// keeps `old`. WAVE_SHL1 0x130: lane i <- i+1, lane63 keeps `old`.
__device__ __forceinline__ float dpp_shr1(float old, float src) {
    return __int_as_float(__builtin_amdgcn_update_dpp(
        __float_as_int(old), __float_as_int(src), 0x138, 0xF, 0xF, false));
}
__device__ __forceinline__ float dpp_shl1(float old, float src) {
    return __int_as_float(__builtin_amdgcn_update_dpp(
        __float_as_int(old), __float_as_int(src), 0x130, 0xF, 0xF, false));
}

__device__ __forceinline__ void glds16(const void* g, void* l) {
    __builtin_amdgcn_global_load_lds(
        (const __attribute__((address_space(1))) void*)g,
        (__attribute__((address_space(3))) void*)l, 16, 0, 0);
}

#define ROT(mi, C, S)                                   \
    {                                                   \
        float L = lo[mi], H = hi[mi];                   \
        lo[mi] = fmaf((C), L, -(S) * H);                \
        hi[mi] = fmaf((C), H, (S) * L);                 \
    }

#define SHIFT()                                                   \
    {                                                             \
        float nlo0 = dpp_shr1(lo[0], lo[3]);                      \
        float nhi3 = dpp_shl1(lo[3], hi[0]);                      \
        float nlo1 = is0 ? hi[0] : lo[0];                         \
        lo[3] = lo[2]; lo[2] = lo[1]; lo[1] = nlo1; lo[0] = nlo0; \
        hi[0] = hi[1]; hi[1] = hi[2]; hi[2] = hi[3]; hi[3] = nhi3;\
    }

#define ROUND(AA, BB)            \
    ROT(0, (AA).x, (AA).y)       \
    ROT(1, (AA).z, (AA).w)       \
    ROT(2, (BB).x, (BB).y)       \
    ROT(3, (BB).z, (BB).w)       \
    SHIFT()

// Stage chunk cix into buffer bix: this wave covers bytes [wave*8K, wave*8K+8K)
// of the 32KB chunk = 8 x 1KB global_load_lds (global src per-lane, LDS dst
// wave-uniform; HW adds lane*16).
#define STAGE(cix, bix)                                              \
    {                                                                \
        const char* g_ = gsrc + (size_t)(cix)*CHUNK_BYTES;           \
        char* l_ = lb + (bix)*CHUNK_BYTES;                           \
        _Pragma("unroll")                                            \
        for (int j = 0; j < 8; ++j)                                  \
            glds16(g_ + j * 1024, l_ + j * 1024);                    \
    }

// Compute NR rounds of chunk in buffer bix; 4-round ds_read ring, static idx.
#define BODY(bix, NR)                                                          \
    {                                                                          \
        float4 RA[4], RB[4];                                                   \
        _Pragma("unroll")                                                      \
        for (int u = 0; u < 4; ++u) {                                          \
            RA[u] = tab[bix][u][0][lane];                                      \
            RB[u] = tab[bix][u][1][lane];                                      \
        }                                                                      \
        _Pragma("unroll")                                                      \
        for (int u = 0; u < (NR); ++u) {                                       \
            ROUND(RA[u & 3], RB[u & 3])                                        \
            if (u + 4 < CHUNK) {                                               \
                RA[u & 3] = tab[bix][u + 4][0][lane];                          \
                RB[u & 3] = tab[bix][u + 4][1][lane];                          \
            }                                                                  \
        }                                                                      \
    }

#define WAITV(n) asm volatile("s_waitcnt vmcnt(" #n ")" ::: "memory")
#define BAR()                               \
    __builtin_amdgcn_s_barrier();           \
    __builtin_amdgcn_sched_barrier(0)

template <bool TAB>
__global__ __launch_bounds__(256, 1) void rotmat_main(const float* __restrict__ x,
                                                      const float* __restrict__ thetas,
                                                      const float2* __restrict__ cs,
                                                      float* __restrict__ out) {
    __shared__ float4 tab[2][CHUNK][2][64];  // [buf][round][plane][lane] = 64KB

    const int lane = threadIdx.x & 63;
    const int wave = threadIdx.x >> 6;
    const int col  = (blockIdx.x << 2) + wave;  // one column per wave
    const int k0   = lane << 2;                 // first pair index of this lane
    const bool is0 = (lane == 0);

    float lo[4], hi[4];
#pragma unroll
    for (int m = 0; m < 4; ++m) {
        lo[m] = x[(k0 + m) * N_COLS + col];
        hi[m] = x[(511 - k0 - m) * N_COLS + col];
    }

    if constexpr (TAB) {
        const char* gsrc = (const char*)cs + (size_t)wave * 8192 + (size_t)lane * 16;
        char* lb = (char*)(&tab[0][0][0][0]) + wave * 8192;

        // Prologue: stage chunks 0,1; wait for 0 (mine); sync all stagers.
        STAGE(0, 0)
        STAGE(1, 1)
        WAITV(8);
        BAR();

        // Chunks 0..29 (b compile-time via 2x unroll). During chunk c: buf[c&1]
        // in use, buf[(c+1)&1] holds c+1. After compute: barrier (reads done),
        // stage c+2 over c's buffer, vmcnt(8) (c+1 fully arrived), barrier.
        for (int t2 = 0; t2 < 15; ++t2) {
            const int c0 = 2 * t2;
            BODY(0, CHUNK)
            BAR();
            STAGE(c0 + 2, 0)
            WAITV(8);
            BAR();
            BODY(1, CHUNK)
            BAR();
            STAGE(c0 + 3, 1)
            WAITV(8);
            BAR();
        }
        // Chunk 30 (buf0); then drain for chunk 31 (staged at t2=14).
        BODY(0, CHUNK)
        WAITV(0);
        BAR();
        // Chunk 31: rounds 496..510 (15 real rounds; round 511 is pad).
        BODY(1, 15)
    } else {
        // Fallback: compute schedule + sincos inline (no workspace table).
        int pu[4], pv[4];
#pragma unroll
        for (int m = 0; m < 4; ++m) {
            pu[m] = (k0 + m == 0) ? 0 : (k0 + m);
            pv[m] = 511 - (k0 + m);
        }
        for (int r = 0; r < 511; ++r) {
#pragma unroll
            for (int m = 0; m < 4; ++m) {
                int i = min(pu[m], pv[m]), j = max(pu[m], pv[m]);
                int t = i * 511 - (i * (i - 1)) / 2 + (j - i - 1);
                float s, c;
                sincosf(thetas[t], &s, &c);
                float sp = (pu[m] < pv[m]) ? s : -s;
                ROT(m, c, sp)
            }
            SHIFT()
#pragma unroll
            for (int m = 0; m < 4; ++m) {
                pu[m] = (k0 + m == 0) ? 0 : ((pu[m] == 1) ? 511 : pu[m] - 1);
                pv[m] = (pv[m] == 1) ? 511 : pv[m] - 1;
            }
        }
    }

    // After 511 shifts the position->row permutation is identity.
#pragma unroll
    for (int m = 0; m < 4; ++m) {
        out[(k0 + m) * N_COLS + col]       = lo[m];
        out[(511 - k0 - m) * N_COLS + col] = hi[m];
    }
}

extern "C" void kernel_launch(void* const* d_in, const int* in_sizes, int n_in,
                              void* d_out, int out_size, void* d_ws, size_t ws_size,
                              hipStream_t stream) {
    const float* x  = (const float*)d_in[0];
    const float* th = (const float*)d_in[1];
    float* out      = (float*)d_out;

    // Table: 512 rounds padded (chunk 31 stages pad round 511; never consumed).
    const size_t need = (size_t)512 * PAIRS * sizeof(float2);  // 1 MiB
    if (ws_size >= need) {
        float2* cs = (float2*)d_ws;
        rotmat_setup<<<511, PAIRS, 0, stream>>>(th, cs);
        rotmat_main<true><<<N_COLS / 4, 256, 0, stream>>>(x, th, cs, out);
    } else {
        rotmat_main<false><<<N_COLS / 4, 256, 0, stream>>>(x, th, nullptr, out);
    }
}